// Round 1
// 2675.910 us; speedup vs baseline: 1.5322x; 1.5322x over previous
//
#include <hip/hip_runtime.h>

#define E_  256
#define H_  512
#define B_  16
#define TE_ 64
#define TD_ 32
#define V_  90000
#define G4_ 2048
#define NBLK_ 128

typedef __attribute__((ext_vector_type(8))) short short8;
typedef __attribute__((ext_vector_type(4))) float f32x4;
typedef _Float16 half2_ __attribute__((ext_vector_type(2)));

__device__ __forceinline__ float sigm(float x) { return 1.f / (1.f + __expf(-x)); }
__device__ __forceinline__ float tanh_(float x) {
  float e = __expf(-2.f * fabsf(x));
  float r = (1.f - e) / (1.f + e);
  return x >= 0.f ? r : -r;
}
__device__ __forceinline__ unsigned short f2bf(float v) {
  union { float f; unsigned u; } c; c.f = v;
  unsigned r = c.u + 0x7FFFu + ((c.u >> 16) & 1u);
  return (unsigned short)(r >> 16);
}
__device__ __forceinline__ unsigned pack2(float a, float b) {
  union { unsigned u; _Float16 h[2]; } p;
  p.h[0] = (_Float16)a; p.h[1] = (_Float16)b;
  return p.u;
}
__device__ __forceinline__ float dot2u(unsigned w, unsigned h, float acc) {
#if __has_builtin(__builtin_amdgcn_fdot2)
  union { unsigned u; half2_ v; } a, b; a.u = w; b.u = h;
  return __builtin_amdgcn_fdot2(a.v, b.v, acc, false);
#else
  union { unsigned u; _Float16 h[2]; } a, b; a.u = w; b.u = h;
  return acc + (float)a.h[0] * (float)b.h[0] + (float)a.h[1] * (float)b.h[1];
#endif
}
__device__ __forceinline__ float dot8(uint4 w, uint4 h, float acc) {
  acc = dot2u(w.x, h.x, acc);
  acc = dot2u(w.y, h.y, acc);
  acc = dot2u(w.z, h.z, acc);
  acc = dot2u(w.w, h.w, acc);
  return acc;
}

// ---------------- f16 pack of recurrent weight blocks, layout [kc][col][8] halves ----------------
// Ue: W_enc rows 256..767   -> [64][2048][8]
// Ud: W_dec rows 256..1279  -> [128][2048][8]   (k = [attn(512)|h(512)])
// Wq: W_query               -> [64][512][8]
// Wa: W_attn                -> [128][512][8]    (k = [h|ctx])
// Wm: W_mem                 -> [64][512][8]
__global__ __launch_bounds__(256) void k_cv(
    const float* __restrict__ W_enc, const float* __restrict__ W_dec,
    const float* __restrict__ W_query, const float* __restrict__ W_attn,
    const float* __restrict__ W_mem,
    uint4* __restrict__ Ue, uint4* __restrict__ Ud, uint4* __restrict__ Wq,
    uint4* __restrict__ Wa, uint4* __restrict__ Wm)
{
  int u = blockIdx.x * 256 + threadIdx.x;
  const float* src; uint4* dst; int C, r0, lu;
  if (u < 131072)      { src = W_enc;   dst = Ue; C = 2048; r0 = 256; lu = u; }
  else if (u < 393216) { src = W_dec;   dst = Ud; C = 2048; r0 = 256; lu = u - 131072; }
  else if (u < 425984) { src = W_query; dst = Wq; C = 512;  r0 = 0;   lu = u - 393216; }
  else if (u < 491520) { src = W_attn;  dst = Wa; C = 512;  r0 = 0;   lu = u - 425984; }
  else                 { src = W_mem;   dst = Wm; C = 512;  r0 = 0;   lu = u - 491520; }
  int kc = lu / C, col = lu - kc * C;
  union { uint4 v; _Float16 h[8]; } p;
  #pragma unroll
  for (int e = 0; e < 8; ++e)
    p.h[e] = (_Float16)src[(size_t)(r0 + kc * 8 + e) * C + col];
  dst[(size_t)kc * C + col] = p.v;
}

// ---------------- x-part of LSTM gates: Xg[tok][2048] = emb[tok]@W[0:256,:] + b ----------------
__global__ __launch_bounds__(256) void k_xg(
    const int* __restrict__ toks, const float* __restrict__ emb,
    const float* __restrict__ W, const float* __restrict__ bias,
    float* __restrict__ Xg)
{
  const int tid = threadIdx.x;
  const int cc = tid & 63;
  const int tg = tid >> 6;
  const int col = blockIdx.x * 64 + cc;
  const int t0 = blockIdx.y * 64 + tg * 16;
  const float* ep[16];
  #pragma unroll
  for (int i = 0; i < 16; ++i) ep[i] = emb + (size_t)toks[t0 + i] * E_;
  float acc[16];
  float bv = bias[col];
  #pragma unroll
  for (int i = 0; i < 16; ++i) acc[i] = bv;
  for (int k4 = 0; k4 < 64; ++k4) {
    float w0 = W[(size_t)(k4 * 4 + 0) * G4_ + col];
    float w1 = W[(size_t)(k4 * 4 + 1) * G4_ + col];
    float w2 = W[(size_t)(k4 * 4 + 2) * G4_ + col];
    float w3 = W[(size_t)(k4 * 4 + 3) * G4_ + col];
    #pragma unroll
    for (int i = 0; i < 16; ++i) {
      float4 e4 = *(const float4*)(ep[i] + k4 * 4);
      acc[i] += e4.x * w0 + e4.y * w1 + e4.z * w2 + e4.w * w3;
    }
  }
  #pragma unroll
  for (int i = 0; i < 16; ++i)
    Xg[(size_t)(t0 + i) * G4_ + col] = acc[i];
}

// ---------------- grid barrier: monotonic counter, agent scope ----------------
__device__ __forceinline__ void gbar(unsigned* bar, unsigned gen) {
  __syncthreads();
  if (threadIdx.x == 0) {
    __threadfence();   // release: flush this XCD's dirty L2 to LLC
    __hip_atomic_fetch_add(bar, 1u, __ATOMIC_RELAXED, __HIP_MEMORY_SCOPE_AGENT);
    const unsigned tgt = gen * (unsigned)NBLK_;
    while (__hip_atomic_load(bar, __ATOMIC_RELAXED, __HIP_MEMORY_SCOPE_AGENT) < tgt)
      __builtin_amdgcn_s_sleep(1);
    __threadfence();   // acquire: invalidate L1 + stale L2 lines
  }
  __syncthreads();
}

// ---------------- fused persistent encoder + keys + decoder ----------------
// 128 blocks x 512 threads, cooperative. Block bid owns h-columns [bid*4, bid*4+4)
// i.e. the 16 gate columns {g*512 + bid*4 + hcl}. Recurrent weights LDS-resident.
// Batched across all 16 batch rows -> each weight slice is read from LDS, fetched
// from HBM exactly once. h / attn vectors exchanged via 16KB global f16 buffers.
// Threads (lower 256): b = t&15, g = (t>>4)&3, hcl = t>>6. Upper 256 take the
// second half of K and reduce through LDS (pacc).
__global__ __launch_bounds__(512) void k_seq(
    const int* __restrict__ enc_len, const float* __restrict__ v_att,
    const float* __restrict__ Xge, const float* __restrict__ Xgd,
    const uint4* __restrict__ Ue, const uint4* __restrict__ Ud,
    const uint4* __restrict__ WqG, const uint4* __restrict__ WaG,
    const uint4* __restrict__ WmG,
    float* __restrict__ keys, unsigned* __restrict__ enc_f16,
    unsigned* __restrict__ hbuf, unsigned* __restrict__ abuf,
    unsigned short* __restrict__ attn_bf, unsigned* __restrict__ bar)
{
  __shared__ __align__(16) uint4 sU[128 * 16];  // 32KB decoder Ud slice  [kc][wl]
  __shared__ __align__(16) uint4 sE[64 * 16];   // 16KB encoder Ue slice  [kc][wl]
  __shared__ __align__(16) uint4 sI[128 * 16];  // 32KB inputs            [kc][b]
  __shared__ __align__(16) uint4 hbB[128];      // [h(64) | ctx(64)] for batch block
  __shared__ float pacc[256];
  __shared__ float shx[4][16];
  __shared__ float shy[4][16];
  __shared__ float pqL[512];
  __shared__ float vlL[512];
  __shared__ float atf[512];
  __shared__ float scp[64][8];
  __shared__ float al64[64];
  __shared__ float ctp[256][2];

  const int tid = threadIdx.x, bid = blockIdx.x;
  const int tlo = tid & 255, hi = tid >> 8;
  const int b = tlo & 15, g = (tlo >> 4) & 3, hcl = tlo >> 6;
  const int wl = hcl * 4 + g;
  const int el = enc_len[b];
  const int elB = (bid < 16) ? enc_len[bid] : 0;
  unsigned gen = 0;

  // ---- preload weight slices into LDS (once), zero abuf, load v_att ----
  for (int idx = tid; idx < 64 * 16; idx += 512) {
    int kc = idx >> 4, w = idx & 15;
    sE[idx] = Ue[(size_t)kc * 2048 + (w & 3) * 512 + bid * 4 + (w >> 2)];
  }
  for (int idx = tid; idx < 128 * 16; idx += 512) {
    int kc = idx >> 4, w = idx & 15;
    sU[idx] = Ud[(size_t)kc * 2048 + (w & 3) * 512 + bid * 4 + (w >> 2)];
  }
  if (tid < 32) abuf[bid * 32 + tid] = 0u;
  if (bid < 16) vlL[tid] = v_att[tid];

  float c = 0.f, hreg = 0.f;
  const uint4* hb4 = (const uint4*)hbuf;
  const uint4* ab4 = (const uint4*)abuf;
  const uint4* ef4 = (const uint4*)enc_f16;

  // ================= encoder: 64 steps, 1 barrier each =================
  for (int t = 0; t < TE_; ++t) {
    for (int idx = tid; idx < 64 * 16; idx += 512) {
      int kc = idx >> 4, bb = idx & 15;
      uint4 v = {0u, 0u, 0u, 0u};
      if (t) v = hb4[bb * 64 + kc];
      sI[idx] = v;
    }
    __syncthreads();
    float acc;
    {
      const int kc0 = hi ? 32 : 0;
      acc = hi ? 0.f
               : Xge[(size_t)(b * TE_ + t) * G4_ + g * 512 + bid * 4 + hcl];
      const uint4* wp = sE + kc0 * 16 + wl;
      const uint4* ip = sI + kc0 * 16 + b;
      #pragma unroll 4
      for (int kc = 0; kc < 32; ++kc)
        acc = dot8(wp[kc * 16], ip[kc * 16], acc);
    }
    if (hi) pacc[tlo] = acc;
    __syncthreads();
    if (!hi) {
      acc += pacc[tlo];
      float v0 = acc;
      float v1 = __shfl_xor(v0, 16);
      float v2 = __shfl_xor(v0, 32);
      float v3 = __shfl_xor(v0, 48);
      float gi = (g == 0) ? v0 : (g == 1) ? v1 : (g == 2) ? v2 : v3;
      float gj = (g == 0) ? v1 : (g == 1) ? v0 : (g == 2) ? v3 : v2;
      float gf = (g == 0) ? v2 : (g == 1) ? v3 : (g == 2) ? v0 : v1;
      float go = (g == 0) ? v3 : (g == 1) ? v2 : (g == 2) ? v1 : v0;
      float c2 = c * sigm(gf + 1.f) + sigm(gi) * tanh_(gj);
      float h2 = tanh_(c2) * sigm(go);
      bool valid = t < el;
      c = valid ? c2 : c;
      hreg = valid ? h2 : hreg;
      if (g == 0) {
        shx[hcl][b] = hreg;
        shy[hcl][b] = valid ? h2 : 0.f;
      }
    }
    __syncthreads();
    if (tid < 32) {
      int bb = tid & 15, pr = tid >> 4;
      hbuf[bb * 256 + bid * 2 + pr] = pack2(shx[2 * pr][bb], shx[2 * pr + 1][bb]);
      enc_f16[(size_t)(bb * TE_ + t) * 256 + bid * 2 + pr] =
          pack2(shy[2 * pr][bb], shy[2 * pr + 1][bb]);
    }
    ++gen; gbar(bar, gen);
  }

  // ================= keys = enc_f16 @ W_mem (block: 8 rows, 512 cols) =================
  {
    for (int idx = tid; idx < 8 * 64; idx += 512) {
      int r = idx >> 6, kc = idx & 63;
      sI[idx] = ef4[(size_t)(bid * 8 + r) * 64 + kc];
    }
    __syncthreads();
    float a8[8] = {0.f, 0.f, 0.f, 0.f, 0.f, 0.f, 0.f, 0.f};
    const uint4* wm = WmG + tid;
    for (int kc = 0; kc < 64; ++kc) {
      uint4 w = wm[(size_t)kc * 512];
      #pragma unroll
      for (int r = 0; r < 8; ++r) a8[r] = dot8(w, sI[r * 64 + kc], a8[r]);
    }
    #pragma unroll
    for (int r = 0; r < 8; ++r)
      keys[(size_t)(bid * 8 + r) * 512 + tid] = a8[r];
    ++gen; gbar(bar, gen);
  }

  // ================= decoder: 32 steps, 2 barriers each =================
  for (int t = 0; t < TD_; ++t) {
    // ---- Phase A: gates = Xgd + [attn|h] @ Ud ; LSTM ; write h2 ----
    for (int idx = tid; idx < 128 * 16; idx += 512) {
      int kc = idx >> 4, bb = idx & 15;
      sI[idx] = (kc < 64) ? ab4[bb * 64 + kc] : hb4[bb * 64 + (kc - 64)];
    }
    __syncthreads();
    float acc;
    {
      const int kc0 = hi ? 64 : 0;
      acc = hi ? 0.f
               : Xgd[(size_t)(b * TD_ + t) * G4_ + g * 512 + bid * 4 + hcl];
      const uint4* wp = sU + kc0 * 16 + wl;
      const uint4* ip = sI + kc0 * 16 + b;
      #pragma unroll 4
      for (int kc = 0; kc < 64; ++kc)
        acc = dot8(wp[kc * 16], ip[kc * 16], acc);
    }
    if (hi) pacc[tlo] = acc;
    __syncthreads();
    if (!hi) {
      acc += pacc[tlo];
      float v0 = acc;
      float v1 = __shfl_xor(v0, 16);
      float v2 = __shfl_xor(v0, 32);
      float v3 = __shfl_xor(v0, 48);
      float gi = (g == 0) ? v0 : (g == 1) ? v1 : (g == 2) ? v2 : v3;
      float gj = (g == 0) ? v1 : (g == 1) ? v0 : (g == 2) ? v3 : v2;
      float gf = (g == 0) ? v2 : (g == 1) ? v3 : (g == 2) ? v0 : v1;
      float go = (g == 0) ? v3 : (g == 1) ? v2 : (g == 2) ? v1 : v0;
      float c2 = c * sigm(gf + 1.f) + sigm(gi) * tanh_(gj);
      float h2 = tanh_(c2) * sigm(go);
      c = c2;
      if (g == 0) shx[hcl][b] = h2;
    }
    __syncthreads();
    if (tid < 32) {
      int bb = tid & 15, pr = tid >> 4;
      hbuf[bb * 256 + bid * 2 + pr] = pack2(shx[2 * pr][bb], shx[2 * pr + 1][bb]);
    }
    ++gen; gbar(bar, gen);

    // ---- Phase B: attention (one block per batch element) ----
    if (bid < 16) {
      if (tid < 64) hbB[tid] = hb4[bid * 64 + tid];
      __syncthreads();
      // pq = h2 @ W_query  (1 col / thread)
      {
        float a = 0.f;
        const uint4* wq = WqG + tid;
        #pragma unroll 4
        for (int kc = 0; kc < 64; ++kc)
          a = dot8(wq[(size_t)kc * 512], hbB[kc], a);
        pqL[tid] = a;
      }
      __syncthreads();
      // scores: 8 threads per t-row
      {
        int tt = tid >> 3, q = tid & 7;
        const float4* kr = (const float4*)(keys + (size_t)(bid * TE_ + tt) * 512 + q * 64);
        const float4* pp = (const float4*)(pqL + q * 64);
        const float4* vp = (const float4*)(vlL + q * 64);
        float s = 0.f;
        #pragma unroll 4
        for (int i = 0; i < 16; ++i) {
          float4 k4 = kr[i], p4 = pp[i], v4 = vp[i];
          s += v4.x * tanh_(k4.x + p4.x) + v4.y * tanh_(k4.y + p4.y)
             + v4.z * tanh_(k4.z + p4.z) + v4.w * tanh_(k4.w + p4.w);
        }
        scp[tt][q] = s;
      }
      __syncthreads();
      if (tid < 64) {
        float sum = 0.f;
        #pragma unroll
        for (int q = 0; q < 8; ++q) sum += scp[tid][q];
        float sc = (tid < elB) ? sum : -1e9f;
        float m = sc;
        for (int o = 32; o > 0; o >>= 1) m = fmaxf(m, __shfl_xor(m, o));
        float p = __expf(sc - m);
        float l = p;
        for (int o = 32; o > 0; o >>= 1) l += __shfl_xor(l, o);
        al64[tid] = p / l;
      }
      __syncthreads();
      // ctx = align @ enc (f16), split t-range across thread halves
      {
        const int j = tlo;
        float c0 = 0.f, c1 = 0.f;
        const unsigned* eb = enc_f16 + (size_t)(bid * TE_ + hi * 32) * 256 + j;
        #pragma unroll 8
        for (int t2 = 0; t2 < 32; ++t2) {
          union { unsigned u; _Float16 h[2]; } u2;
          u2.u = eb[(size_t)t2 * 256];
          float a = al64[hi * 32 + t2];
          c0 += a * (float)u2.h[0];
          c1 += a * (float)u2.h[1];
        }
        if (hi) { ctp[j][0] = c0; ctp[j][1] = c1; }
        __syncthreads();
        if (!hi)
          ((unsigned*)hbB)[256 + j] = pack2(c0 + ctp[j][0], c1 + ctp[j][1]);
        __syncthreads();
      }
      // attn2 = [h2|ctx] @ W_attn (1 col / thread)
      {
        float a = 0.f;
        const uint4* wa = WaG + tid;
        #pragma unroll 2
        for (int kc = 0; kc < 128; ++kc)
          a = dot8(wa[(size_t)kc * 512], hbB[kc], a);
        attn_bf[(size_t)(bid * TD_ + t) * 512 + tid] = f2bf(a);
        atf[tid] = a;
      }
      __syncthreads();
      if (tid < 256) abuf[bid * 256 + tid] = pack2(atf[2 * tid], atf[2 * tid + 1]);
    }
    ++gen; gbar(bar, gen);
  }
}

// ---------------- projection: logits[512][90000] = attn_bf @ bf16(W_proj), masked ----------------
__global__ __launch_bounds__(512) void k_proj(
    const float* __restrict__ Wp, const unsigned short* __restrict__ Abf,
    const int* __restrict__ dec_len_g, float* __restrict__ out)
{
  __shared__ unsigned short Al[512 * 40];
  __shared__ unsigned short Bl[128 * 40];
  __shared__ int dl[16];
  const int tid = threadIdx.x;
  const int n0 = blockIdx.x * 128;
  const int wave = tid >> 6, lane = tid & 63;
  if (tid < 16) dl[tid] = dec_len_g[tid];
  f32x4 acc[4][8] = {};
  for (int kc = 0; kc < 16; ++kc) {
    const int k0 = kc * 32;
    {
      const unsigned short* src = Abf + (size_t)tid * 512 + k0;
      unsigned short* dst = Al + tid * 40;
      *(uint4*)(dst)      = *(const uint4*)(src);
      *(uint4*)(dst + 8)  = *(const uint4*)(src + 8);
      *(uint4*)(dst + 16) = *(const uint4*)(src + 16);
      *(uint4*)(dst + 24) = *(const uint4*)(src + 24);
    }
    {
      int kk = tid >> 4;
      int nn = (tid & 15) * 8;
      const float* src = Wp + (size_t)(k0 + kk) * V_ + n0 + nn;
      #pragma unroll
      for (int j = 0; j < 8; ++j) {
        float v = (n0 + nn + j < V_) ? src[j] : 0.f;
        Bl[(nn + j) * 40 + kk] = f2bf(v);
      }
    }
    __syncthreads();
    short8 bfr[8];
    #pragma unroll
    for (int nt = 0; nt < 8; ++nt)
      bfr[nt] = *(const short8*)&Bl[(nt * 16 + (lane & 15)) * 40 + (lane >> 4) * 8];
    #pragma unroll
    for (int mt = 0; mt < 4; ++mt) {
      short8 af = *(const short8*)&Al[(wave * 64 + mt * 16 + (lane & 15)) * 40 + (lane >> 4) * 8];
      #pragma unroll
      for (int nt = 0; nt < 8; ++nt)
        acc[mt][nt] = __builtin_amdgcn_mfma_f32_16x16x32_bf16(af, bfr[nt], acc[mt][nt], 0, 0, 0);
    }
    __syncthreads();
  }
  #pragma unroll
  for (int mt = 0; mt < 4; ++mt) {
    #pragma unroll
    for (int e = 0; e < 4; ++e) {
      int r = wave * 64 + mt * 16 + ((lane >> 4) << 2) + e;
      bool valid = (r & 31) < dl[r >> 5];
      #pragma unroll
      for (int nt = 0; nt < 8; ++nt) {
        int gcol = n0 + nt * 16 + (lane & 15);
        if (gcol < V_)
          out[(size_t)r * V_ + gcol] = valid ? acc[mt][nt][e] : 0.f;
      }
    }
  }
}

extern "C" void kernel_launch(void* const* d_in, const int* in_sizes, int n_in,
                              void* d_out, int out_size, void* d_ws, size_t ws_size,
                              hipStream_t stream) {
  const int* enc_in   = (const int*)d_in[0];
  const int* dec_in   = (const int*)d_in[1];
  const int* enc_len  = (const int*)d_in[2];
  const int* dec_len  = (const int*)d_in[3];
  const float* emb    = (const float*)d_in[4];
  const float* W_enc  = (const float*)d_in[5];
  const float* b_enc  = (const float*)d_in[6];
  const float* W_dec  = (const float*)d_in[7];
  const float* b_dec  = (const float*)d_in[8];
  const float* W_mem  = (const float*)d_in[9];
  const float* W_query= (const float*)d_in[10];
  const float* v_att  = (const float*)d_in[11];
  const float* W_attn = (const float*)d_in[12];
  const float* W_proj = (const float*)d_in[13];
  float* out = (float*)d_out;
  char* ws = (char*)d_ws;

  float* Xge          = (float*)(ws + 0);          //  8 MB
  float* Xgd          = (float*)(ws + 8388608);    //  4 MB
  uint4* Ue           = (uint4*)(ws + 12582912);   //  2 MB
  uint4* Ud           = (uint4*)(ws + 14680064);   //  4 MB
  uint4* Wq           = (uint4*)(ws + 18874368);   // 0.5 MB
  uint4* Wa           = (uint4*)(ws + 19398656);   //  1 MB
  uint4* Wm           = (uint4*)(ws + 20447232);   // 0.5 MB
  unsigned* hbuf      = (unsigned*)(ws + 20971520);// 16 KB (reuses old enc_out slot)
  unsigned* abuf      = (unsigned*)(ws + 20987904);// 16 KB
  unsigned* bar       = (unsigned*)(ws + 21004288);// 64 B, zeroed per launch
  unsigned* enc_f16   = (unsigned*)(ws + 23068672);//  1 MB
  float* keys         = (float*)(ws + 24117248);   //  2 MB
  unsigned short* attn_bf = (unsigned short*)(ws + 26214400); // 0.5 MB

  k_cv<<<2048, 256, 0, stream>>>(W_enc, W_dec, W_query, W_attn, W_mem,
                                 Ue, Ud, Wq, Wa, Wm);
  k_xg<<<dim3(32, 16), 256, 0, stream>>>(enc_in, emb, W_enc, b_enc, Xge);
  k_xg<<<dim3(32, 8),  256, 0, stream>>>(dec_in, emb, W_dec, b_dec, Xgd);
  hipMemsetAsync(bar, 0, 64, stream);
  {
    const int* a0 = enc_len; const float* a1 = v_att;
    const float* a2 = Xge;   const float* a3 = Xgd;
    const uint4* a4 = Ue;    const uint4* a5 = Ud;
    const uint4* a6 = Wq;    const uint4* a7 = Wa;
    const uint4* a8 = Wm;
    float* a9 = keys;        unsigned* a10 = enc_f16;
    unsigned* a11 = hbuf;    unsigned* a12 = abuf;
    unsigned short* a13 = attn_bf; unsigned* a14 = bar;
    void* kargs[] = { &a0, &a1, &a2, &a3, &a4, &a5, &a6, &a7, &a8,
                      &a9, &a10, &a11, &a12, &a13, &a14 };
    hipLaunchCooperativeKernel((void*)k_seq, dim3(NBLK_), dim3(512),
                               kargs, 0, stream);
  }
  k_proj<<<704, 512, 0, stream>>>(W_proj, attn_bf, dec_len, out);
}

// Round 2
// 2186.065 us; speedup vs baseline: 1.8755x; 1.2241x over previous
//
#include <hip/hip_runtime.h>

#define E_  256
#define H_  512
#define B_  16
#define TE_ 64
#define TD_ 32
#define V_  90000
#define G4_ 2048
#define NBLK_ 128

typedef __attribute__((ext_vector_type(8))) short short8;
typedef __attribute__((ext_vector_type(4))) float f32x4;
typedef _Float16 half2_ __attribute__((ext_vector_type(2)));

__device__ __forceinline__ float sigm(float x) { return 1.f / (1.f + __expf(-x)); }
__device__ __forceinline__ float tanh_(float x) {
  float e = __expf(-2.f * fabsf(x));
  float r = (1.f - e) / (1.f + e);
  return x >= 0.f ? r : -r;
}
__device__ __forceinline__ unsigned short f2bf(float v) {
  union { float f; unsigned u; } c; c.f = v;
  unsigned r = c.u + 0x7FFFu + ((c.u >> 16) & 1u);
  return (unsigned short)(r >> 16);
}
__device__ __forceinline__ unsigned pack2(float a, float b) {
  union { unsigned u; _Float16 h[2]; } p;
  p.h[0] = (_Float16)a; p.h[1] = (_Float16)b;
  return p.u;
}
__device__ __forceinline__ float dot2u(unsigned w, unsigned h, float acc) {
#if __has_builtin(__builtin_amdgcn_fdot2)
  union { unsigned u; half2_ v; } a, b; a.u = w; b.u = h;
  return __builtin_amdgcn_fdot2(a.v, b.v, acc, false);
#else
  union { unsigned u; _Float16 h[2]; } a, b; a.u = w; b.u = h;
  return acc + (float)a.h[0] * (float)b.h[0] + (float)a.h[1] * (float)b.h[1];
#endif
}
__device__ __forceinline__ float dot8(uint4 w, uint4 h, float acc) {
  acc = dot2u(w.x, h.x, acc);
  acc = dot2u(w.y, h.y, acc);
  acc = dot2u(w.z, h.z, acc);
  acc = dot2u(w.w, h.w, acc);
  return acc;
}

// relaxed agent-scope (device-coherent, LLC-direct, no cache-maintenance) ops
__device__ __forceinline__ unsigned ld_ag(const unsigned* p) {
  return __hip_atomic_load(p, __ATOMIC_RELAXED, __HIP_MEMORY_SCOPE_AGENT);
}
__device__ __forceinline__ void st_ag(unsigned* p, unsigned v) {
  __hip_atomic_store(p, v, __ATOMIC_RELAXED, __HIP_MEMORY_SCOPE_AGENT);
}

// ---------------- f16 pack of recurrent weight blocks, layout [kc][col][8] halves ----------------
__global__ __launch_bounds__(256) void k_cv(
    const float* __restrict__ W_enc, const float* __restrict__ W_dec,
    const float* __restrict__ W_query, const float* __restrict__ W_attn,
    const float* __restrict__ W_mem,
    uint4* __restrict__ Ue, uint4* __restrict__ Ud, uint4* __restrict__ Wq,
    uint4* __restrict__ Wa, uint4* __restrict__ Wm)
{
  int u = blockIdx.x * 256 + threadIdx.x;
  const float* src; uint4* dst; int C, r0, lu;
  if (u < 131072)      { src = W_enc;   dst = Ue; C = 2048; r0 = 256; lu = u; }
  else if (u < 393216) { src = W_dec;   dst = Ud; C = 2048; r0 = 256; lu = u - 131072; }
  else if (u < 425984) { src = W_query; dst = Wq; C = 512;  r0 = 0;   lu = u - 393216; }
  else if (u < 491520) { src = W_attn;  dst = Wa; C = 512;  r0 = 0;   lu = u - 425984; }
  else                 { src = W_mem;   dst = Wm; C = 512;  r0 = 0;   lu = u - 491520; }
  int kc = lu / C, col = lu - kc * C;
  union { uint4 v; _Float16 h[8]; } p;
  #pragma unroll
  for (int e = 0; e < 8; ++e)
    p.h[e] = (_Float16)src[(size_t)(r0 + kc * 8 + e) * C + col];
  dst[(size_t)kc * C + col] = p.v;
}

// ---------------- x-part of LSTM gates ----------------
__global__ __launch_bounds__(256) void k_xg(
    const int* __restrict__ toks, const float* __restrict__ emb,
    const float* __restrict__ W, const float* __restrict__ bias,
    float* __restrict__ Xg)
{
  const int tid = threadIdx.x;
  const int cc = tid & 63;
  const int tg = tid >> 6;
  const int col = blockIdx.x * 64 + cc;
  const int t0 = blockIdx.y * 64 + tg * 16;
  const float* ep[16];
  #pragma unroll
  for (int i = 0; i < 16; ++i) ep[i] = emb + (size_t)toks[t0 + i] * E_;
  float acc[16];
  float bv = bias[col];
  #pragma unroll
  for (int i = 0; i < 16; ++i) acc[i] = bv;
  for (int k4 = 0; k4 < 64; ++k4) {
    float w0 = W[(size_t)(k4 * 4 + 0) * G4_ + col];
    float w1 = W[(size_t)(k4 * 4 + 1) * G4_ + col];
    float w2 = W[(size_t)(k4 * 4 + 2) * G4_ + col];
    float w3 = W[(size_t)(k4 * 4 + 3) * G4_ + col];
    #pragma unroll
    for (int i = 0; i < 16; ++i) {
      float4 e4 = *(const float4*)(ep[i] + k4 * 4);
      acc[i] += e4.x * w0 + e4.y * w1 + e4.z * w2 + e4.w * w3;
    }
  }
  #pragma unroll
  for (int i = 0; i < 16; ++i)
    Xg[(size_t)(t0 + i) * G4_ + col] = acc[i];
}

// ---------------- grid barriers ----------------
// lite: no cache maintenance. Correct because all cross-block data in the steady
// loop moves via relaxed agent-scope atomics (sc0/sc1, LLC-coherent), and
// __syncthreads() drains each wave's vmcnt before thread 0 increments the flag.
__device__ __forceinline__ void gbar_lite(unsigned* bar, unsigned gen) {
  __syncthreads();
  if (threadIdx.x == 0) {
    asm volatile("s_waitcnt vmcnt(0) lgkmcnt(0)" ::: "memory");
    __hip_atomic_fetch_add(bar, 1u, __ATOMIC_RELAXED, __HIP_MEMORY_SCOPE_AGENT);
    const unsigned tgt = gen * (unsigned)NBLK_;
    while (__hip_atomic_load(bar, __ATOMIC_RELAXED, __HIP_MEMORY_SCOPE_AGENT) < tgt)
      __builtin_amdgcn_s_sleep(1);
  }
  __syncthreads();
}
// heavy: full release/acquire (L2 writeback + invalidate) for bulk plain-stored
// data (enc_f16, keys) crossing XCDs. Used exactly twice.
__device__ __forceinline__ void gbar_heavy(unsigned* bar, unsigned gen) {
  __syncthreads();
  if (threadIdx.x == 0) {
    __threadfence();
    __hip_atomic_fetch_add(bar, 1u, __ATOMIC_RELAXED, __HIP_MEMORY_SCOPE_AGENT);
    const unsigned tgt = gen * (unsigned)NBLK_;
    while (__hip_atomic_load(bar, __ATOMIC_RELAXED, __HIP_MEMORY_SCOPE_AGENT) < tgt)
      __builtin_amdgcn_s_sleep(1);
    __threadfence();
  }
  __syncthreads();
}

// ---------------- fused persistent encoder + keys + decoder ----------------
// hbuf is double-buffered by step parity (hb0/hb1) to close the stage-vs-write
// race window. abuf is single-buffered (writer and reader separated by 2 barriers).
__global__ __launch_bounds__(512) void k_seq(
    const int* __restrict__ enc_len, const float* __restrict__ v_att,
    const float* __restrict__ Xge, const float* __restrict__ Xgd,
    const uint4* __restrict__ Ue, const uint4* __restrict__ Ud,
    const uint4* __restrict__ WqG, const uint4* __restrict__ WaG,
    const uint4* __restrict__ WmG,
    float* __restrict__ keys, unsigned* __restrict__ enc_f16,
    unsigned* __restrict__ hbuf, unsigned* __restrict__ abuf,
    unsigned short* __restrict__ attn_bf, unsigned* __restrict__ bar)
{
  __shared__ __align__(16) uint4 sU[128 * 16];  // 32KB decoder Ud slice  [kc][wl]
  __shared__ __align__(16) uint4 sE[64 * 16];   // 16KB encoder Ue slice  [kc][wl]
  __shared__ __align__(16) uint4 sI[128 * 16];  // 32KB inputs            [kc][b]
  __shared__ __align__(16) unsigned sHC[512];   // [h(256) | ctx(256)] packed pairs
  __shared__ float pacc[256];
  __shared__ float shx[4][16];
  __shared__ float shy[4][16];
  __shared__ float pqL[512];
  __shared__ float vlL[512];
  __shared__ float atf[512];
  __shared__ float scp[64][8];
  __shared__ float al64[64];
  __shared__ float ctp[256][2];

  const int tid = threadIdx.x, bid = blockIdx.x;
  const int tlo = tid & 255, hi = tid >> 8;
  const int b = tlo & 15, g = (tlo >> 4) & 3, hcl = tlo >> 6;
  const int wl = hcl * 4 + g;
  const int el = enc_len[b];
  const int elB = (bid < 16) ? enc_len[bid] : 0;
  unsigned gen = 0;
  unsigned* const hb0 = hbuf;
  unsigned* const hb1 = hbuf + 4096;
  unsigned* sIu = (unsigned*)sI;

  // ---- preload weight slices into LDS (once), zero abuf, load v_att ----
  for (int idx = tid; idx < 64 * 16; idx += 512) {
    int kc = idx >> 4, w = idx & 15;
    sE[idx] = Ue[(size_t)kc * 2048 + (w & 3) * 512 + bid * 4 + (w >> 2)];
  }
  for (int idx = tid; idx < 128 * 16; idx += 512) {
    int kc = idx >> 4, w = idx & 15;
    sU[idx] = Ud[(size_t)kc * 2048 + (w & 3) * 512 + bid * 4 + (w >> 2)];
  }
  if (tid < 32) st_ag(abuf + bid * 32 + tid, 0u);
  if (bid < 16) vlL[tid] = v_att[tid];

  float c = 0.f, hreg = 0.f;
  const uint4* ef4 = (const uint4*)enc_f16;

  // ================= encoder: 64 steps, 1 lite barrier each (last heavy) =================
  for (int t = 0; t < TE_; ++t) {
    unsigned* hb_prev = (t & 1) ? hb0 : hb1;
    unsigned* hb_cur  = (t & 1) ? hb1 : hb0;
    if (t == 0) {
      for (int idx = tid; idx < 4096; idx += 512) sIu[idx] = 0u;
    } else {
      for (int idx = tid; idx < 4096; idx += 512) {
        int w = idx & 3, bb = (idx >> 2) & 15, kc = idx >> 6;
        sIu[idx] = ld_ag(hb_prev + bb * 256 + kc * 4 + w);
      }
    }
    __syncthreads();
    float acc;
    {
      const int kc0 = hi ? 32 : 0;
      acc = hi ? 0.f
               : Xge[(size_t)(b * TE_ + t) * G4_ + g * 512 + bid * 4 + hcl];
      const uint4* wp = sE + kc0 * 16 + wl;
      const uint4* ip = sI + kc0 * 16 + b;
      #pragma unroll 4
      for (int kc = 0; kc < 32; ++kc)
        acc = dot8(wp[kc * 16], ip[kc * 16], acc);
    }
    if (hi) pacc[tlo] = acc;
    __syncthreads();
    if (!hi) {
      acc += pacc[tlo];
      float v0 = acc;
      float v1 = __shfl_xor(v0, 16);
      float v2 = __shfl_xor(v0, 32);
      float v3 = __shfl_xor(v0, 48);
      float gi = (g == 0) ? v0 : (g == 1) ? v1 : (g == 2) ? v2 : v3;
      float gj = (g == 0) ? v1 : (g == 1) ? v0 : (g == 2) ? v3 : v2;
      float gf = (g == 0) ? v2 : (g == 1) ? v3 : (g == 2) ? v0 : v1;
      float go = (g == 0) ? v3 : (g == 1) ? v2 : (g == 2) ? v1 : v0;
      float c2 = c * sigm(gf + 1.f) + sigm(gi) * tanh_(gj);
      float h2 = tanh_(c2) * sigm(go);
      bool valid = t < el;
      c = valid ? c2 : c;
      hreg = valid ? h2 : hreg;
      if (g == 0) {
        shx[hcl][b] = hreg;
        shy[hcl][b] = valid ? h2 : 0.f;
      }
    }
    __syncthreads();
    if (tid < 32) {
      int bb = tid & 15, pr = tid >> 4;
      st_ag(hb_cur + bb * 256 + bid * 2 + pr, pack2(shx[2 * pr][bb], shx[2 * pr + 1][bb]));
      enc_f16[(size_t)(bb * TE_ + t) * 256 + bid * 2 + pr] =
          pack2(shy[2 * pr][bb], shy[2 * pr + 1][bb]);
    }
    ++gen;
    if (t == TE_ - 1) gbar_heavy(bar, gen);   // enc_f16 -> keys-phase readers
    else              gbar_lite(bar, gen);
  }

  // ================= keys = enc_f16 @ W_mem (block: 8 rows, 512 cols) =================
  {
    for (int idx = tid; idx < 8 * 64; idx += 512) {
      int r = idx >> 6, kc = idx & 63;
      sI[idx] = ef4[(size_t)(bid * 8 + r) * 64 + kc];
    }
    __syncthreads();
    float a8[8] = {0.f, 0.f, 0.f, 0.f, 0.f, 0.f, 0.f, 0.f};
    const uint4* wm = WmG + tid;
    for (int kc = 0; kc < 64; ++kc) {
      uint4 w = wm[(size_t)kc * 512];
      #pragma unroll
      for (int r = 0; r < 8; ++r) a8[r] = dot8(w, sI[r * 64 + kc], a8[r]);
    }
    #pragma unroll
    for (int r = 0; r < 8; ++r)
      keys[(size_t)(bid * 8 + r) * 512 + tid] = a8[r];
    ++gen; gbar_heavy(bar, gen);   // keys -> decoder phase-B readers
  }

  // ================= decoder: 32 steps, 2 lite barriers each =================
  for (int t = 0; t < TD_; ++t) {
    unsigned* hb_prev = (t & 1) ? hb0 : hb1;   // t=0 reads enc final (hb1)
    unsigned* hb_cur  = (t & 1) ? hb1 : hb0;
    // ---- Phase A: gates = Xgd + [attn|h] @ Ud ; LSTM ; write h2 ----
    for (int idx = tid; idx < 8192; idx += 512) {
      int w = idx & 3, bb = (idx >> 2) & 15, kc = idx >> 6;
      sIu[idx] = (kc < 64) ? ld_ag(abuf + bb * 256 + kc * 4 + w)
                           : ld_ag(hb_prev + bb * 256 + (kc - 64) * 4 + w);
    }
    __syncthreads();
    float acc;
    {
      const int kc0 = hi ? 64 : 0;
      acc = hi ? 0.f
               : Xgd[(size_t)(b * TD_ + t) * G4_ + g * 512 + bid * 4 + hcl];
      const uint4* wp = sU + kc0 * 16 + wl;
      const uint4* ip = sI + kc0 * 16 + b;
      #pragma unroll 4
      for (int kc = 0; kc < 64; ++kc)
        acc = dot8(wp[kc * 16], ip[kc * 16], acc);
    }
    if (hi) pacc[tlo] = acc;
    __syncthreads();
    if (!hi) {
      acc += pacc[tlo];
      float v0 = acc;
      float v1 = __shfl_xor(v0, 16);
      float v2 = __shfl_xor(v0, 32);
      float v3 = __shfl_xor(v0, 48);
      float gi = (g == 0) ? v0 : (g == 1) ? v1 : (g == 2) ? v2 : v3;
      float gj = (g == 0) ? v1 : (g == 1) ? v0 : (g == 2) ? v3 : v2;
      float gf = (g == 0) ? v2 : (g == 1) ? v3 : (g == 2) ? v0 : v1;
      float go = (g == 0) ? v3 : (g == 1) ? v2 : (g == 2) ? v1 : v0;
      float c2 = c * sigm(gf + 1.f) + sigm(gi) * tanh_(gj);
      float h2 = tanh_(c2) * sigm(go);
      c = c2;
      if (g == 0) shx[hcl][b] = h2;
    }
    __syncthreads();
    if (tid < 32) {
      int bb = tid & 15, pr = tid >> 4;
      st_ag(hb_cur + bb * 256 + bid * 2 + pr, pack2(shx[2 * pr][bb], shx[2 * pr + 1][bb]));
    }
    ++gen; gbar_lite(bar, gen);

    // ---- Phase B: attention (one block per batch element) ----
    if (bid < 16) {
      if (tid < 256) sHC[tid] = ld_ag(hb_cur + bid * 256 + tid);
      __syncthreads();
      // pq = h2 @ W_query  (1 col / thread)
      {
        float a = 0.f;
        const uint4* hv = (const uint4*)sHC;
        const uint4* wq = WqG + tid;
        #pragma unroll 4
        for (int kc = 0; kc < 64; ++kc)
          a = dot8(wq[(size_t)kc * 512], hv[kc], a);
        pqL[tid] = a;
      }
      __syncthreads();
      // scores: 8 threads per t-row
      {
        int tt = tid >> 3, q = tid & 7;
        const float4* kr = (const float4*)(keys + (size_t)(bid * TE_ + tt) * 512 + q * 64);
        const float4* pp = (const float4*)(pqL + q * 64);
        const float4* vp = (const float4*)(vlL + q * 64);
        float s = 0.f;
        #pragma unroll 4
        for (int i = 0; i < 16; ++i) {
          float4 k4 = kr[i], p4 = pp[i], v4 = vp[i];
          s += v4.x * tanh_(k4.x + p4.x) + v4.y * tanh_(k4.y + p4.y)
             + v4.z * tanh_(k4.z + p4.z) + v4.w * tanh_(k4.w + p4.w);
        }
        scp[tt][q] = s;
      }
      __syncthreads();
      if (tid < 64) {
        float sum = 0.f;
        #pragma unroll
        for (int q = 0; q < 8; ++q) sum += scp[tid][q];
        float sc = (tid < elB) ? sum : -1e9f;
        float m = sc;
        for (int o = 32; o > 0; o >>= 1) m = fmaxf(m, __shfl_xor(m, o));
        float p = __expf(sc - m);
        float l = p;
        for (int o = 32; o > 0; o >>= 1) l += __shfl_xor(l, o);
        al64[tid] = p / l;
      }
      __syncthreads();
      // ctx = align @ enc (f16), split t-range across thread halves
      {
        const int j = tlo;
        float c0 = 0.f, c1 = 0.f;
        const unsigned* eb = enc_f16 + (size_t)(bid * TE_ + hi * 32) * 256 + j;
        #pragma unroll 8
        for (int t2 = 0; t2 < 32; ++t2) {
          union { unsigned u; _Float16 h[2]; } u2;
          u2.u = eb[(size_t)t2 * 256];
          float a = al64[hi * 32 + t2];
          c0 += a * (float)u2.h[0];
          c1 += a * (float)u2.h[1];
        }
        if (hi) { ctp[j][0] = c0; ctp[j][1] = c1; }
        __syncthreads();
        if (!hi)
          sHC[256 + j] = pack2(c0 + ctp[j][0], c1 + ctp[j][1]);
        __syncthreads();
      }
      // attn2 = [h2|ctx] @ W_attn (1 col / thread)
      {
        float a = 0.f;
        const uint4* iv2 = (const uint4*)sHC;
        const uint4* wa = WaG + tid;
        #pragma unroll 2
        for (int kc = 0; kc < 128; ++kc)
          a = dot8(wa[(size_t)kc * 512], iv2[kc], a);
        attn_bf[(size_t)(bid * TD_ + t) * 512 + tid] = f2bf(a);
        atf[tid] = a;
      }
      __syncthreads();
      if (tid < 256) st_ag(abuf + bid * 256 + tid, pack2(atf[2 * tid], atf[2 * tid + 1]));
    }
    ++gen; gbar_lite(bar, gen);
  }
}

// ---------------- projection: logits[512][90000] = attn_bf @ bf16(W_proj), masked ----------------
__global__ __launch_bounds__(512) void k_proj(
    const float* __restrict__ Wp, const unsigned short* __restrict__ Abf,
    const int* __restrict__ dec_len_g, float* __restrict__ out)
{
  __shared__ unsigned short Al[512 * 40];
  __shared__ unsigned short Bl[128 * 40];
  __shared__ int dl[16];
  const int tid = threadIdx.x;
  const int n0 = blockIdx.x * 128;
  const int wave = tid >> 6, lane = tid & 63;
  if (tid < 16) dl[tid] = dec_len_g[tid];
  f32x4 acc[4][8] = {};
  for (int kc = 0; kc < 16; ++kc) {
    const int k0 = kc * 32;
    {
      const unsigned short* src = Abf + (size_t)tid * 512 + k0;
      unsigned short* dst = Al + tid * 40;
      *(uint4*)(dst)      = *(const uint4*)(src);
      *(uint4*)(dst + 8)  = *(const uint4*)(src + 8);
      *(uint4*)(dst + 16) = *(const uint4*)(src + 16);
      *(uint4*)(dst + 24) = *(const uint4*)(src + 24);
    }
    {
      int kk = tid >> 4;
      int nn = (tid & 15) * 8;
      const float* src = Wp + (size_t)(k0 + kk) * V_ + n0 + nn;
      #pragma unroll
      for (int j = 0; j < 8; ++j) {
        float v = (n0 + nn + j < V_) ? src[j] : 0.f;
        Bl[(nn + j) * 40 + kk] = f2bf(v);
      }
    }
    __syncthreads();
    short8 bfr[8];
    #pragma unroll
    for (int nt = 0; nt < 8; ++nt)
      bfr[nt] = *(const short8*)&Bl[(nt * 16 + (lane & 15)) * 40 + (lane >> 4) * 8];
    #pragma unroll
    for (int mt = 0; mt < 4; ++mt) {
      short8 af = *(const short8*)&Al[(wave * 64 + mt * 16 + (lane & 15)) * 40 + (lane >> 4) * 8];
      #pragma unroll
      for (int nt = 0; nt < 8; ++nt)
        acc[mt][nt] = __builtin_amdgcn_mfma_f32_16x16x32_bf16(af, bfr[nt], acc[mt][nt], 0, 0, 0);
    }
    __syncthreads();
  }
  #pragma unroll
  for (int mt = 0; mt < 4; ++mt) {
    #pragma unroll
    for (int e = 0; e < 4; ++e) {
      int r = wave * 64 + mt * 16 + ((lane >> 4) << 2) + e;
      bool valid = (r & 31) < dl[r >> 5];
      #pragma unroll
      for (int nt = 0; nt < 8; ++nt) {
        int gcol = n0 + nt * 16 + (lane & 15);
        if (gcol < V_)
          out[(size_t)r * V_ + gcol] = valid ? acc[mt][nt][e] : 0.f;
      }
    }
  }
}

extern "C" void kernel_launch(void* const* d_in, const int* in_sizes, int n_in,
                              void* d_out, int out_size, void* d_ws, size_t ws_size,
                              hipStream_t stream) {
  const int* enc_in   = (const int*)d_in[0];
  const int* dec_in   = (const int*)d_in[1];
  const int* enc_len  = (const int*)d_in[2];
  const int* dec_len  = (const int*)d_in[3];
  const float* emb    = (const float*)d_in[4];
  const float* W_enc  = (const float*)d_in[5];
  const float* b_enc  = (const float*)d_in[6];
  const float* W_dec  = (const float*)d_in[7];
  const float* b_dec  = (const float*)d_in[8];
  const float* W_mem  = (const float*)d_in[9];
  const float* W_query= (const float*)d_in[10];
  const float* v_att  = (const float*)d_in[11];
  const float* W_attn = (const float*)d_in[12];
  const float* W_proj = (const float*)d_in[13];
  float* out = (float*)d_out;
  char* ws = (char*)d_ws;

  float* Xge          = (float*)(ws + 0);          //  8 MB
  float* Xgd          = (float*)(ws + 8388608);    //  4 MB
  uint4* Ue           = (uint4*)(ws + 12582912);   //  2 MB
  uint4* Ud           = (uint4*)(ws + 14680064);   //  4 MB
  uint4* Wq           = (uint4*)(ws + 18874368);   // 0.5 MB
  uint4* Wa           = (uint4*)(ws + 19398656);   //  1 MB
  uint4* Wm           = (uint4*)(ws + 20447232);   // 0.5 MB
  unsigned* hbuf      = (unsigned*)(ws + 20971520);// 32 KB (double-buffered h)
  unsigned* abuf      = (unsigned*)(ws + 21004288);// 16 KB
  unsigned* bar       = (unsigned*)(ws + 21020672);// 64 B, zeroed per launch
  unsigned* enc_f16   = (unsigned*)(ws + 23068672);//  1 MB
  float* keys         = (float*)(ws + 24117248);   //  2 MB
  unsigned short* attn_bf = (unsigned short*)(ws + 26214400); // 0.5 MB

  k_cv<<<2048, 256, 0, stream>>>(W_enc, W_dec, W_query, W_attn, W_mem,
                                 Ue, Ud, Wq, Wa, Wm);
  k_xg<<<dim3(32, 16), 256, 0, stream>>>(enc_in, emb, W_enc, b_enc, Xge);
  k_xg<<<dim3(32, 8),  256, 0, stream>>>(dec_in, emb, W_dec, b_dec, Xgd);
  hipMemsetAsync(bar, 0, 64, stream);
  {
    const int* a0 = enc_len; const float* a1 = v_att;
    const float* a2 = Xge;   const float* a3 = Xgd;
    const uint4* a4 = Ue;    const uint4* a5 = Ud;
    const uint4* a6 = Wq;    const uint4* a7 = Wa;
    const uint4* a8 = Wm;
    float* a9 = keys;        unsigned* a10 = enc_f16;
    unsigned* a11 = hbuf;    unsigned* a12 = abuf;
    unsigned short* a13 = attn_bf; unsigned* a14 = bar;
    void* kargs[] = { &a0, &a1, &a2, &a3, &a4, &a5, &a6, &a7, &a8,
                      &a9, &a10, &a11, &a12, &a13, &a14 };
    hipLaunchCooperativeKernel((void*)k_seq, dim3(NBLK_), dim3(512),
                               kargs, 0, stream);
  }
  k_proj<<<704, 512, 0, stream>>>(W_proj, attn_bf, dec_len, out);
}